// Round 10
// baseline (4143.225 us; speedup 1.0000x reference)
//
#include <hip/hip_runtime.h>
#include <hip/hip_cooperative_groups.h>
#include <hip/hip_bf16.h>
#include <math.h>

constexpr int EMBD  = 512;
constexpr int HID   = 1024;
constexpr int NOUT  = 5;
constexpr int SEQ   = 512;
constexpr int BATCH = 64;

constexpr int NBLK = 64;    // blocks; block owns 16 hidden cols
constexpr int NTHR = 512;   // 8 waves: (mp in 0..1) x (kq in 0..3)
constexpr int JPB  = 16;    // hidden cols per block
constexpr int NS   = 4;     // h ring slots

constexpr unsigned long long SENT = 0xFFFFFFFFFFFFFFFFull;  // 4x bf16 NaN

typedef __attribute__((ext_vector_type(8))) short bf16x8;
typedef __attribute__((ext_vector_type(4))) float f32x4;

__device__ inline unsigned short f2bf(float f) {
    __hip_bfloat16 h = __float2bfloat16(f);
    return *reinterpret_cast<unsigned short*>(&h);
}

__device__ inline bf16x8 cvt8v(f32x4 a, f32x4 b) {
    bf16x8 r;
#pragma unroll
    for (int i = 0; i < 4; i++) { __hip_bfloat16 h = __float2bfloat16(a[i]); r[i]     = *reinterpret_cast<short*>(&h); }
#pragma unroll
    for (int i = 0; i < 4; i++) { __hip_bfloat16 h = __float2bfloat16(b[i]); r[4 + i] = *reinterpret_cast<short*>(&h); }
    return r;
}

// Agent-scope (MALL-coherent) 8B ops: h exchange and x reads.
__device__ inline unsigned long long load_a8(const unsigned short* p) {
    return __hip_atomic_load((const unsigned long long*)p,
                             __ATOMIC_RELAXED, __HIP_MEMORY_SCOPE_AGENT);
}
__device__ inline void store_a8(unsigned short* p, unsigned long long v) {
    __hip_atomic_store((unsigned long long*)p, v,
                       __ATOMIC_RELAXED, __HIP_MEMORY_SCOPE_AGENT);
}
__device__ inline bf16x8 load_frag(const unsigned short* p) {
    union { unsigned long long u[2]; bf16x8 v; } r;
    r.u[0] = load_a8(p);
    r.u[1] = load_a8(p + 4);
    return r.v;
}
__device__ inline bf16x8 mkfrag(unsigned long long lo, unsigned long long hi) {
    union { unsigned long long u[2]; bf16x8 v; } r;
    r.u[0] = lo; r.u[1] = hi;
    return r.v;
}

__device__ inline float sigm(float x) { return 1.f / (1.f + __expf(-x)); }
__device__ inline float ftanh(float x) { return 1.f - 2.f / (1.f + __expf(2.f * x)); }

// ---------------------------------------------------------------------------
// Pack W [K, 3072] fp32 -> bf16 MFMA B-fragments, layout [g][nt][kt][lane][8]
// ---------------------------------------------------------------------------
__global__ __launch_bounds__(256) void pack_w(const float* __restrict__ W,
                                              unsigned short* __restrict__ out,
                                              int K) {
    const int nkt = K / 32;
    long idx = (long)blockIdx.x * 256 + threadIdx.x;
    const long total = (long)NBLK * 3 * nkt * 64;
    if (idx >= total) return;
    const int lane = idx & 63;
    long rest = idx >> 6;
    const int kt = rest % nkt; rest /= nkt;
    const int nt = rest % 3;
    const int g  = rest / 3;
    const int k0  = kt * 32 + (lane >> 4) * 8;
    const int col = nt * HID + g * JPB + (lane & 15);
    unsigned short* o = out + idx * 8;
#pragma unroll
    for (int i = 0; i < 8; i++)
        o[i] = f2bf(W[(long)(k0 + i) * 3072 + col]);
}

// ---------------------------------------------------------------------------
// One-shot embedding into A-FRAGMENT layout:
// xfrag[t][bt(4)][kt(16)][lane(64)][8]: value = x_t[bt*16+(lane&15)]
//                                               [kt*32+(lane>>4)*8+i]
// ---------------------------------------------------------------------------
__global__ __launch_bounds__(256) void embed_x(const int* __restrict__ text,
                                               const float* __restrict__ emb,
                                               unsigned short* __restrict__ xfrag) {
    long idx = (long)blockIdx.x * 256 + threadIdx.x;
    if (idx >= (long)SEQ * 4 * 16 * 64) return;
    const int lane = idx & 63;
    const int kt   = (idx >> 6) & 15;
    const int bt   = (idx >> 10) & 3;
    const int t    = (int)(idx >> 12);
    const int b    = bt * 16 + (lane & 15);
    const int e0   = kt * 32 + (lane >> 4) * 8;
    const int tok  = text[t * BATCH + b];
    const float* s = emb + (long)tok * EMBD + e0;
    *(bf16x8*)(xfrag + idx * 8) = cvt8v(*(const f32x4*)s, *(const f32x4*)(s + 4));
}

// ---------------------------------------------------------------------------
// Persistent GRU, sentinel-ring dataflow (NO per-step grid barrier):
// h ring: 4 slots of fragment-layout [bt(4)][kt(32)][lane(64)][8] bf16.
// Step t: consume slot (t+3)%4 (h of t-1) by POLLING chunks != SENT;
//         produce into slot t%4 (plain 8B agent stores, no drain/flag);
//         re-sentinel own chunks in slot (t+2)%4 (same-thread same-address
//         coherence orders these; block skew provably <= 1 step).
// Per step: 2 __syncthreads (publish->gate, gate->store). That's all.
// ---------------------------------------------------------------------------
__global__ void __launch_bounds__(NTHR, 2) gru_mfma(
    const unsigned short* __restrict__ xfrag,  // [SEQ][4][16][64][8] bf16
    const float*          __restrict__ b_ih,   // [3072]
    const float*          __restrict__ b_hh,   // [3072]
    const float*          __restrict__ fc_W,   // [HID][NOUT]
    const float*          __restrict__ fc_b,   // [NOUT]
    const unsigned short* __restrict__ whh_f,  // [64][3][32][64][8]
    const unsigned short* __restrict__ wih_f,  // [64][3][16][64][8]
    unsigned short*       __restrict__ hring,  // [NS][4][32][64][8] bf16
    int*                  __restrict__ flags,  // [64] (zeroed) - init only
    float*                __restrict__ out)    // [BATCH][NOUT] (zeroed)
{
    const int g    = blockIdx.x;
    const int tid  = threadIdx.x;
    const int lane = tid & 63;
    const int w    = tid >> 6;
    const int mp   = w >> 2;   // 0..1
    const int kq   = w & 3;    // 0..3
    const int l16  = lane & 15;
    const int lhi  = lane >> 4;

    __shared__ float red[8][8][256];            // 64 KB partial buffer
    __shared__ unsigned short hx[64][20];       // padded h' transpose buffer

    constexpr int HFRAG = 4 * 32 * 64 * 8;      // ushorts per slot (128 KB)

    // ---- init: this block's own 256 chunks in each slot:
    //      slots 0..2 = SENT, slot 3 = zeros (h_{-1} = 0) ----
    for (int i = tid; i < 4 * 256; i += NTHR) {
        const int slot = i >> 8;
        const int c    = i & 255;
        const int mt   = c >> 6;
        const int ln   = c & 63;
        const long off = (((long)mt * 32 + (g >> 1)) * 64) * 8 + 256 * (g & 1) + ln * 4;
        store_a8(hring + (long)slot * HFRAG + off, (slot == 3) ? 0ull : SENT);
    }

    // biases for this lane's j (used by gate waves)
    const int jg = g * JPB + l16;
    const float bir  = b_ih[jg],           bhr = b_hh[jg];
    const float biz  = b_ih[HID + jg],     bhz = b_hh[HID + jg];
    const float bin_ = b_ih[2 * HID + jg], bhn = b_hh[2 * HID + jg];

    const bool gateW  = (kq < 2);
    const bool storeW = (kq >= 2);
    const int  mtG    = mp * 2 + kq;         // gate wave's btile (kq<2)
    const int  mtS    = mp * 2 + (kq - 2);   // storer wave's btile (kq>=2)
    float hp[4] = {0.f, 0.f, 0.f, 0.f};      // fp32 carry (gate waves)

    bf16x8 xa0[4], xa1[4];
    auto loadX = [&](int t) {
        const unsigned short* base = xfrag + (long)t * (4 * 16 * 64 * 8);
#pragma unroll
        for (int kk = 0; kk < 4; kk++) {
            const int kt = kq * 4 + kk;
            xa0[kk] = load_frag(base + (((2 * mp + 0) * 16 + kt) * 64 + lane) * 8);
            xa1[kk] = load_frag(base + (((2 * mp + 1) * 16 + kt) * 64 + lane) * 8);
        }
    };

    // storer-wave addressing: lane s covers consumer-lane cl = s>>1, half s&1
    const int sb  = mtS * 16 + ((lane >> 1) & 15);              // source b row
    const int sjl = ((lane >> 1) >> 4) * 8 + 4 * (lane & 1);    // source j-local
    const long sdst = (((long)mtS * 32 + (g >> 1)) * 64) * 8 + 256 * (g & 1) + lane * 4;

    const unsigned short* whh_g = whh_f + (long)g * 3 * 32 * 64 * 8;
    const unsigned short* wih_g = wih_f + (long)g * 3 * 16 * 64 * 8;

    // ---- one-time init barrier (slot-3 zeros + sentinels visible) ----
    asm volatile("s_waitcnt vmcnt(0)" ::: "memory");
    __syncthreads();
    if (tid == 0)
        __hip_atomic_store(&flags[g], 1, __ATOMIC_RELAXED, __HIP_MEMORY_SCOPE_AGENT);
    if (tid < 64) {
        int f = __hip_atomic_load(&flags[tid], __ATOMIC_RELAXED, __HIP_MEMORY_SCOPE_AGENT);
        while (__any(f < 1)) {
            __builtin_amdgcn_s_sleep(1);
            f = __hip_atomic_load(&flags[tid], __ATOMIC_RELAXED, __HIP_MEMORY_SCOPE_AGENT);
        }
    }
    __syncthreads();

    for (int t = 0; t < SEQ; ++t) {
        const unsigned short* hr = hring + (long)((t + 3) & 3) * HFRAG;  // h_{t-1}
        unsigned short*       hw = hring + (long)(t & 3) * HFRAG;        // h_t out
        unsigned short*       hs = hring + (long)((t + 2) & 3) * HFRAG;  // re-sentinel

        // ---- x loads for this step: issued first, complete during h poll ----
        loadX(t);

        // ---- poll-load h fragments: the poll IS the data load (1 RTT) ----
        const unsigned short* p0 = hr + (((long)(2 * mp + 0) * 32 + kq * 8) * 64 + lane) * 8;
        const unsigned short* p1 = hr + (((long)(2 * mp + 1) * 32 + kq * 8) * 64 + lane) * 8;
        unsigned long long a0lo[8], a0hi[8], a1lo[8], a1hi[8];
        while (true) {
            bool ok = true;
#pragma unroll
            for (int kk = 0; kk < 8; kk++) {
                a0lo[kk] = load_a8(p0 + kk * 512);
                a0hi[kk] = load_a8(p0 + kk * 512 + 4);
                a1lo[kk] = load_a8(p1 + kk * 512);
                a1hi[kk] = load_a8(p1 + kk * 512 + 4);
            }
#pragma unroll
            for (int kk = 0; kk < 8; kk++)
                ok = ok && (a0lo[kk] != SENT) && (a0hi[kk] != SENT)
                        && (a1lo[kk] != SENT) && (a1hi[kk] != SENT);
            if (__all(ok)) break;
            __builtin_amdgcn_s_sleep(1);
        }
        bf16x8 ha0[8], ha1[8];
#pragma unroll
        for (int kk = 0; kk < 8; kk++) {
            ha0[kk] = mkfrag(a0lo[kk], a0hi[kk]);
            ha1[kk] = mkfrag(a1lo[kk], a1hi[kk]);
        }

        f32x4 aR0 = {0,0,0,0}, aR1 = {0,0,0,0};
        f32x4 aZ0 = {0,0,0,0}, aZ1 = {0,0,0,0};
        f32x4 aGh0 = {0,0,0,0}, aGh1 = {0,0,0,0};
        f32x4 aGi0 = {0,0,0,0}, aGi1 = {0,0,0,0};

        // ---- gi: x_t @ W_ih ----
#pragma unroll
        for (int kk = 0; kk < 4; kk++) {
            const unsigned short* bp = wih_g + (((long)(kq * 4 + kk)) * 64 + lane) * 8;
            const bf16x8 bR = *(const bf16x8*)(bp);
            const bf16x8 bZ = *(const bf16x8*)(bp + 16 * 64 * 8);
            const bf16x8 bN = *(const bf16x8*)(bp + 2 * 16 * 64 * 8);
            aR0  = __builtin_amdgcn_mfma_f32_16x16x32_bf16(xa0[kk], bR, aR0, 0, 0, 0);
            aR1  = __builtin_amdgcn_mfma_f32_16x16x32_bf16(xa1[kk], bR, aR1, 0, 0, 0);
            aZ0  = __builtin_amdgcn_mfma_f32_16x16x32_bf16(xa0[kk], bZ, aZ0, 0, 0, 0);
            aZ1  = __builtin_amdgcn_mfma_f32_16x16x32_bf16(xa1[kk], bZ, aZ1, 0, 0, 0);
            aGi0 = __builtin_amdgcn_mfma_f32_16x16x32_bf16(xa0[kk], bN, aGi0, 0, 0, 0);
            aGi1 = __builtin_amdgcn_mfma_f32_16x16x32_bf16(xa1[kk], bN, aGi1, 0, 0, 0);
        }

        // ---- gh: h_t @ W_hh ----
#pragma unroll
        for (int kk = 0; kk < 8; kk++) {
            const int kt = kq * 8 + kk;
            const unsigned short* bp = whh_g + (((long)kt) * 64 + lane) * 8;
            const bf16x8 bR = *(const bf16x8*)(bp);
            const bf16x8 bZ = *(const bf16x8*)(bp + 32 * 64 * 8);
            const bf16x8 bN = *(const bf16x8*)(bp + 2 * 32 * 64 * 8);
            aR0  = __builtin_amdgcn_mfma_f32_16x16x32_bf16(ha0[kk], bR, aR0, 0, 0, 0);
            aR1  = __builtin_amdgcn_mfma_f32_16x16x32_bf16(ha1[kk], bR, aR1, 0, 0, 0);
            aZ0  = __builtin_amdgcn_mfma_f32_16x16x32_bf16(ha0[kk], bZ, aZ0, 0, 0, 0);
            aZ1  = __builtin_amdgcn_mfma_f32_16x16x32_bf16(ha1[kk], bZ, aZ1, 0, 0, 0);
            aGh0 = __builtin_amdgcn_mfma_f32_16x16x32_bf16(ha0[kk], bN, aGh0, 0, 0, 0);
            aGh1 = __builtin_amdgcn_mfma_f32_16x16x32_bf16(ha1[kk], bN, aGh1, 0, 0, 0);
        }

        // ---- publish partials ----
        *(f32x4*)&red[w][0][lane * 4] = aR0;
        *(f32x4*)&red[w][1][lane * 4] = aR1;
        *(f32x4*)&red[w][2][lane * 4] = aZ0;
        *(f32x4*)&red[w][3][lane * 4] = aZ1;
        *(f32x4*)&red[w][4][lane * 4] = aGh0;
        *(f32x4*)&red[w][5][lane * 4] = aGh1;
        *(f32x4*)&red[w][6][lane * 4] = aGi0;
        *(f32x4*)&red[w][7][lane * 4] = aGi1;
        __syncthreads();

        // ---- gate waves: reduce one btile, gates, carry, write hx ----
        if (gateW) {
            const int s = kq;
            f32x4 R  = {0,0,0,0}, Z = {0,0,0,0}, Gh = {0,0,0,0}, Gi = {0,0,0,0};
#pragma unroll
            for (int q = 0; q < 4; q++) {
                const int src = mp * 4 + q;
                R  += *(const f32x4*)&red[src][0 + s][lane * 4];
                Z  += *(const f32x4*)&red[src][2 + s][lane * 4];
                Gh += *(const f32x4*)&red[src][4 + s][lane * 4];
                Gi += *(const f32x4*)&red[src][6 + s][lane * 4];
            }
#pragma unroll
            for (int r = 0; r < 4; r++) {
                const float rr = sigm(R[r] + bir + bhr);
                const float zz = sigm(Z[r] + biz + bhz);
                const float nn = ftanh(Gi[r] + bin_ + rr * (Gh[r] + bhn));
                const float hn = (1.f - zz) * nn + zz * hp[r];
                hp[r] = hn;
                hx[mtG * 16 + lhi * 4 + r][l16] = f2bf(hn);
            }
        }
        __syncthreads();

        // ---- storer waves: emit h' chunk + re-sentinel own chunk in the
        //      slot 2 steps ahead (same thread, same address set) ----
        if (storeW) {
            const unsigned long long v = *(const unsigned long long*)&hx[sb][sjl];
            store_a8(hw + sdst, v);
            store_a8(hs + sdst, SENT);
        }
        // no sync, no drain, no flag: consumers poll the data itself
    }

    // ---- epilogue: block-local FC partial over its 16 cols, atomicAdd out ----
    __syncthreads();
    float (*hsl)[JPB] = reinterpret_cast<float(*)[JPB]>(&red[0][0][0]);  // [64][16]
    if (gateW) {
#pragma unroll
        for (int r = 0; r < 4; r++) {
            const int b = mtG * 16 + lhi * 4 + r;
            hsl[b][l16] = hp[r];
        }
    }
    __syncthreads();
    if (tid < BATCH * NOUT) {
        const int b = tid / NOUT, o = tid - b * NOUT;
        float acc = (g == 0) ? fc_b[o] : 0.0f;
#pragma unroll
        for (int jl = 0; jl < JPB; jl++)
            acc += hsl[b][jl] * fc_W[(g * JPB + jl) * NOUT + o];
        atomicAdd(&out[tid], acc);
    }
}

// ---------------------------------------------------------------------------
extern "C" void kernel_launch(void* const* d_in, const int* in_sizes, int n_in,
                              void* d_out, int out_size, void* d_ws, size_t ws_size,
                              hipStream_t stream) {
    const int*   text = (const int*)  d_in[0];
    const float* emb  = (const float*)d_in[1];
    const float* W_ih = (const float*)d_in[2];
    const float* W_hh = (const float*)d_in[3];
    const float* b_ih = (const float*)d_in[4];
    const float* b_hh = (const float*)d_in[5];
    const float* fc_W = (const float*)d_in[6];
    const float* fc_b = (const float*)d_in[7];
    float* out = (float*)d_out;

    // ws layout (bytes):
    //   flags [64] int (rounded to 4096)           : 4096
    //   hring [4][4][32][64][8] bf16               : 524288
    //   whh_f [64][3][32][64][8] bf16              : 6291456
    //   wih_f [64][3][16][64][8] bf16              : 3145728
    //   xfrag [512][4][16][64][8] bf16             : 33554432   (~43.6 MB)
    char* ws = (char*)d_ws;
    int*            flags = (int*)(ws);
    unsigned short* hring = (unsigned short*)(ws + 4096);
    unsigned short* whh_f = (unsigned short*)(ws + 4096 + 524288);
    unsigned short* wih_f = (unsigned short*)(ws + 4096 + 524288 + 6291456);
    unsigned short* xfrag = (unsigned short*)(ws + 4096 + 524288 + 6291456 + 3145728);

    hipMemsetAsync(flags, 0, 4096, stream);
    hipMemsetAsync(out, 0, (size_t)out_size * sizeof(float), stream);

    const long nfrag_hh = (long)NBLK * 3 * 32 * 64;   // 393216
    const long nfrag_ih = (long)NBLK * 3 * 16 * 64;   // 196608
    pack_w<<<(int)((nfrag_hh + 255) / 256), 256, 0, stream>>>(W_hh, whh_f, HID);
    pack_w<<<(int)((nfrag_ih + 255) / 256), 256, 0, stream>>>(W_ih, wih_f, EMBD);

    const long nx = (long)SEQ * 4 * 16 * 64;
    embed_x<<<(int)((nx + 255) / 256), 256, 0, stream>>>(text, emb, xfrag);

    void* args[] = { (void*)&xfrag, (void*)&b_ih, (void*)&b_hh,
                     (void*)&fc_W, (void*)&fc_b, (void*)&whh_f, (void*)&wih_f,
                     (void*)&hring, (void*)&flags, (void*)&out };
    hipLaunchCooperativeKernel((void*)gru_mfma, dim3(NBLK), dim3(NTHR), args, 0, stream);
}

// Round 11
// 4068.634 us; speedup vs baseline: 1.0183x; 1.0183x over previous
//
#include <hip/hip_runtime.h>
#include <hip/hip_cooperative_groups.h>
#include <hip/hip_bf16.h>
#include <math.h>

constexpr int EMBD  = 512;
constexpr int HID   = 1024;
constexpr int NOUT  = 5;
constexpr int SEQ   = 512;
constexpr int BATCH = 64;

constexpr int NBLK = 64;    // blocks; block owns 16 hidden cols
constexpr int NTHR = 512;   // 8 waves: (mp in 0..1) x (kq in 0..3)
constexpr int JPB  = 16;    // hidden cols per block

typedef __attribute__((ext_vector_type(8))) short bf16x8;
typedef __attribute__((ext_vector_type(4))) float f32x4;

__device__ inline unsigned short f2bf(float f) {
    __hip_bfloat16 h = __float2bfloat16(f);
    return *reinterpret_cast<unsigned short*>(&h);
}

__device__ inline bf16x8 cvt8v(f32x4 a, f32x4 b) {
    bf16x8 r;
#pragma unroll
    for (int i = 0; i < 4; i++) { __hip_bfloat16 h = __float2bfloat16(a[i]); r[i]     = *reinterpret_cast<short*>(&h); }
#pragma unroll
    for (int i = 0; i < 4; i++) { __hip_bfloat16 h = __float2bfloat16(b[i]); r[4 + i] = *reinterpret_cast<short*>(&h); }
    return r;
}

// Agent-scope (MALL-coherent) 8B ops: h exchange and x reads.
__device__ inline unsigned long long load_a8(const unsigned short* p) {
    return __hip_atomic_load((const unsigned long long*)p,
                             __ATOMIC_RELAXED, __HIP_MEMORY_SCOPE_AGENT);
}
__device__ inline void store_a8(unsigned short* p, unsigned long long v) {
    __hip_atomic_store((unsigned long long*)p, v,
                       __ATOMIC_RELAXED, __HIP_MEMORY_SCOPE_AGENT);
}
__device__ inline bf16x8 load_frag(const unsigned short* p) {
    union { unsigned long long u[2]; bf16x8 v; } r;
    r.u[0] = load_a8(p);
    r.u[1] = load_a8(p + 4);
    return r.v;
}

__device__ inline float sigm(float x) { return 1.f / (1.f + __expf(-x)); }
__device__ inline float ftanh(float x) { return 1.f - 2.f / (1.f + __expf(2.f * x)); }

// ---------------------------------------------------------------------------
// Pack W [K, 3072] fp32 -> bf16 MFMA B-fragments, layout [g][nt][kt][lane][8]
// ---------------------------------------------------------------------------
__global__ __launch_bounds__(256) void pack_w(const float* __restrict__ W,
                                              unsigned short* __restrict__ out,
                                              int K) {
    const int nkt = K / 32;
    long idx = (long)blockIdx.x * 256 + threadIdx.x;
    const long total = (long)NBLK * 3 * nkt * 64;
    if (idx >= total) return;
    const int lane = idx & 63;
    long rest = idx >> 6;
    const int kt = rest % nkt; rest /= nkt;
    const int nt = rest % 3;
    const int g  = rest / 3;
    const int k0  = kt * 32 + (lane >> 4) * 8;
    const int col = nt * HID + g * JPB + (lane & 15);
    unsigned short* o = out + idx * 8;
#pragma unroll
    for (int i = 0; i < 8; i++)
        o[i] = f2bf(W[(long)(k0 + i) * 3072 + col]);
}

// ---------------------------------------------------------------------------
// One-shot embedding into A-FRAGMENT layout:
// xfrag[t][bt(4)][kt(16)][lane(64)][8]
// ---------------------------------------------------------------------------
__global__ __launch_bounds__(256) void embed_x(const int* __restrict__ text,
                                               const float* __restrict__ emb,
                                               unsigned short* __restrict__ xfrag) {
    long idx = (long)blockIdx.x * 256 + threadIdx.x;
    if (idx >= (long)SEQ * 4 * 16 * 64) return;
    const int lane = idx & 63;
    const int kt   = (idx >> 6) & 15;
    const int bt   = (idx >> 10) & 3;
    const int t    = (int)(idx >> 12);
    const int b    = bt * 16 + (lane & 15);
    const int e0   = kt * 32 + (lane >> 4) * 8;
    const int tok  = text[t * BATCH + b];
    const float* s = emb + (long)tok * EMBD + e0;
    *(bf16x8*)(xfrag + idx * 8) = cvt8v(*(const f32x4*)s, *(const f32x4*)(s + 4));
}

// ---------------------------------------------------------------------------
// Persistent GRU, dependency-narrowed flag waits + gi seam overlap.
// h ring: 4 slots [bt(4)][kt(32)][lane(64)][8] bf16. Step t reads slot
// (t+3)&3 (= h_{t-1}), writes slot t&3. flags[g]=t+2 after step t (drained).
// Wave kq waits only its 16 producers (blocks 16kq..16kq+15) at flag>=t+1.
// gi for step t+1 + x load run at the seam (after flag store) to cover
// flag propagation. Block-level dep is still all-to-all -> skew <= 1 step
// -> 4-slot ring reuse is race-free.
// ---------------------------------------------------------------------------
__global__ void __launch_bounds__(NTHR, 2) gru_mfma(
    const unsigned short* __restrict__ xfrag,  // [SEQ][4][16][64][8] bf16
    const float*          __restrict__ b_ih,   // [3072]
    const float*          __restrict__ b_hh,   // [3072]
    const float*          __restrict__ fc_W,   // [HID][NOUT]
    const float*          __restrict__ fc_b,   // [NOUT]
    const unsigned short* __restrict__ whh_f,  // [64][3][32][64][8]
    const unsigned short* __restrict__ wih_f,  // [64][3][16][64][8]
    unsigned short*       __restrict__ hring,  // [4][4][32][64][8] bf16
    int*                  __restrict__ flags,  // [64] (zeroed)
    float*                __restrict__ out)    // [BATCH][NOUT] (zeroed)
{
    const int g    = blockIdx.x;
    const int tid  = threadIdx.x;
    const int lane = tid & 63;
    const int w    = tid >> 6;
    const int mp   = w >> 2;   // 0..1
    const int kq   = w & 3;    // 0..3
    const int l16  = lane & 15;
    const int lhi  = lane >> 4;

    __shared__ float red[8][8][256];            // 64 KB partial buffer
    __shared__ unsigned short hx[64][20];       // padded h' transpose buffer

    constexpr int HFRAG = 4 * 32 * 64 * 8;      // ushorts per slot (128 KB)

    // ---- init: zero this block's own 256 chunks of slot 3 (h_{-1}=0) ----
    for (int i = tid; i < 256; i += NTHR) {
        const int mt = i >> 6;
        const int ln = i & 63;
        const long off = (((long)mt * 32 + (g >> 1)) * 64) * 8 + 256 * (g & 1) + ln * 4;
        store_a8(hring + (long)3 * HFRAG + off, 0ull);
    }
    asm volatile("s_waitcnt vmcnt(0)" ::: "memory");
    __syncthreads();
    if (tid == 0)
        __hip_atomic_store(&flags[g], 1, __ATOMIC_RELAXED, __HIP_MEMORY_SCOPE_AGENT);

    // biases for this lane's j (used by gate waves)
    const int jg = g * JPB + l16;
    const float bir  = b_ih[jg],           bhr = b_hh[jg];
    const float biz  = b_ih[HID + jg],     bhz = b_hh[HID + jg];
    const float bin_ = b_ih[2 * HID + jg], bhn = b_hh[2 * HID + jg];

    const bool gateW  = (kq < 2);
    const bool storeW = (kq >= 2);
    const int  mtG    = mp * 2 + kq;         // gate wave's btile (kq<2)
    const int  mtS    = mp * 2 + (kq - 2);   // storer wave's btile (kq>=2)
    float hp[4] = {0.f, 0.f, 0.f, 0.f};      // fp32 carry (gate waves)

    bf16x8 xa0[4], xa1[4];
    auto loadX = [&](int t) {
        const unsigned short* base = xfrag + (long)t * (4 * 16 * 64 * 8);
#pragma unroll
        for (int kk = 0; kk < 4; kk++) {
            const int kt = kq * 4 + kk;
            xa0[kk] = load_frag(base + (((2 * mp + 0) * 16 + kt) * 64 + lane) * 8);
            xa1[kk] = load_frag(base + (((2 * mp + 1) * 16 + kt) * 64 + lane) * 8);
        }
    };

    // storer-wave addressing: lane s covers consumer-lane cl = s>>1, half s&1
    const int sb  = mtS * 16 + ((lane >> 1) & 15);              // source b row
    const int sjl = ((lane >> 1) >> 4) * 8 + 4 * (lane & 1);    // source j-local
    const long sdst = (((long)mtS * 32 + (g >> 1)) * 64) * 8 + 256 * (g & 1) + lane * 4;

    const unsigned short* whh_g = whh_f + (long)g * 3 * 32 * 64 * 8;
    const unsigned short* wih_g = wih_f + (long)g * 3 * 16 * 64 * 8;

    // accumulators carry gi across the loop seam
    f32x4 aR0, aR1, aZ0, aZ1, aGh0, aGh1, aGi0, aGi1;

    auto giStep = [&](int t) {
        loadX(t);
        aR0 = f32x4{0,0,0,0};  aR1 = f32x4{0,0,0,0};
        aZ0 = f32x4{0,0,0,0};  aZ1 = f32x4{0,0,0,0};
        aGh0 = f32x4{0,0,0,0}; aGh1 = f32x4{0,0,0,0};
        aGi0 = f32x4{0,0,0,0}; aGi1 = f32x4{0,0,0,0};
#pragma unroll
        for (int kk = 0; kk < 4; kk++) {
            const unsigned short* bp = wih_g + (((long)(kq * 4 + kk)) * 64 + lane) * 8;
            const bf16x8 bR = *(const bf16x8*)(bp);
            const bf16x8 bZ = *(const bf16x8*)(bp + 16 * 64 * 8);
            const bf16x8 bN = *(const bf16x8*)(bp + 2 * 16 * 64 * 8);
            aR0  = __builtin_amdgcn_mfma_f32_16x16x32_bf16(xa0[kk], bR, aR0, 0, 0, 0);
            aR1  = __builtin_amdgcn_mfma_f32_16x16x32_bf16(xa1[kk], bR, aR1, 0, 0, 0);
            aZ0  = __builtin_amdgcn_mfma_f32_16x16x32_bf16(xa0[kk], bZ, aZ0, 0, 0, 0);
            aZ1  = __builtin_amdgcn_mfma_f32_16x16x32_bf16(xa1[kk], bZ, aZ1, 0, 0, 0);
            aGi0 = __builtin_amdgcn_mfma_f32_16x16x32_bf16(xa0[kk], bN, aGi0, 0, 0, 0);
            aGi1 = __builtin_amdgcn_mfma_f32_16x16x32_bf16(xa1[kk], bN, aGi1, 0, 0, 0);
        }
    };

    giStep(0);   // prologue: gi for t=0 (overlaps init flag propagation)

    const int fidx = 16 * kq + (lane & 15);   // own-quarter producer flags

    for (int t = 0; t < SEQ; ++t) {
        const unsigned short* hr = hring + (long)((t + 3) & 3) * HFRAG;  // h_{t-1}
        unsigned short*       hw = hring + (long)(t & 3) * HFRAG;        // h_t

        // ---- wait ONLY own-quarter producers (16 blocks, 1 cache line) ----
        {
            int f = __hip_atomic_load(&flags[fidx], __ATOMIC_RELAXED, __HIP_MEMORY_SCOPE_AGENT);
            while (__any(f < t + 1)) {
                __builtin_amdgcn_s_sleep(1);
                f = __hip_atomic_load(&flags[fidx], __ATOMIC_RELAXED, __HIP_MEMORY_SCOPE_AGENT);
            }
        }

        // ---- h fragment loads (1 MALL RTT, pipelined) ----
        bf16x8 ha0[8], ha1[8];
#pragma unroll
        for (int kk = 0; kk < 8; kk++) {
            const int kt = kq * 8 + kk;
            ha0[kk] = load_frag(hr + (((long)(2 * mp + 0) * 32 + kt) * 64 + lane) * 8);
            ha1[kk] = load_frag(hr + (((long)(2 * mp + 1) * 32 + kt) * 64 + lane) * 8);
        }

        // ---- gh: h_t @ W_hh (accs already hold gi) ----
#pragma unroll
        for (int kk = 0; kk < 8; kk++) {
            const int kt = kq * 8 + kk;
            const unsigned short* bp = whh_g + (((long)kt) * 64 + lane) * 8;
            const bf16x8 bR = *(const bf16x8*)(bp);
            const bf16x8 bZ = *(const bf16x8*)(bp + 32 * 64 * 8);
            const bf16x8 bN = *(const bf16x8*)(bp + 2 * 32 * 64 * 8);
            aR0  = __builtin_amdgcn_mfma_f32_16x16x32_bf16(ha0[kk], bR, aR0, 0, 0, 0);
            aR1  = __builtin_amdgcn_mfma_f32_16x16x32_bf16(ha1[kk], bR, aR1, 0, 0, 0);
            aZ0  = __builtin_amdgcn_mfma_f32_16x16x32_bf16(ha0[kk], bZ, aZ0, 0, 0, 0);
            aZ1  = __builtin_amdgcn_mfma_f32_16x16x32_bf16(ha1[kk], bZ, aZ1, 0, 0, 0);
            aGh0 = __builtin_amdgcn_mfma_f32_16x16x32_bf16(ha0[kk], bN, aGh0, 0, 0, 0);
            aGh1 = __builtin_amdgcn_mfma_f32_16x16x32_bf16(ha1[kk], bN, aGh1, 0, 0, 0);
        }

        // ---- publish partials ----
        *(f32x4*)&red[w][0][lane * 4] = aR0;
        *(f32x4*)&red[w][1][lane * 4] = aR1;
        *(f32x4*)&red[w][2][lane * 4] = aZ0;
        *(f32x4*)&red[w][3][lane * 4] = aZ1;
        *(f32x4*)&red[w][4][lane * 4] = aGh0;
        *(f32x4*)&red[w][5][lane * 4] = aGh1;
        *(f32x4*)&red[w][6][lane * 4] = aGi0;
        *(f32x4*)&red[w][7][lane * 4] = aGi1;
        __syncthreads();

        // ---- gate waves: reduce one btile, gates, carry, write hx ----
        if (gateW) {
            const int s = kq;
            f32x4 R  = {0,0,0,0}, Z = {0,0,0,0}, Gh = {0,0,0,0}, Gi = {0,0,0,0};
#pragma unroll
            for (int q = 0; q < 4; q++) {
                const int src = mp * 4 + q;
                R  += *(const f32x4*)&red[src][0 + s][lane * 4];
                Z  += *(const f32x4*)&red[src][2 + s][lane * 4];
                Gh += *(const f32x4*)&red[src][4 + s][lane * 4];
                Gi += *(const f32x4*)&red[src][6 + s][lane * 4];
            }
#pragma unroll
            for (int r = 0; r < 4; r++) {
                const float rr = sigm(R[r] + bir + bhr);
                const float zz = sigm(Z[r] + biz + bhz);
                const float nn = ftanh(Gi[r] + bin_ + rr * (Gh[r] + bhn));
                const float hn = (1.f - zz) * nn + zz * hp[r];
                hp[r] = hn;
                hx[mtG * 16 + lhi * 4 + r][l16] = f2bf(hn);
            }
        }
        __syncthreads();

        // ---- storer waves: emit h' chunk into ring slot t&3 + drain ----
        if (storeW) {
            const unsigned long long v = *(const unsigned long long*)&hx[sb][sjl];
            store_a8(hw + sdst, v);
            asm volatile("s_waitcnt vmcnt(0)" ::: "memory");
        }
        __syncthreads();

        // ---- flag this block done with step t; overlap gi(t+1) with the
        //      flag propagation + other blocks' tails ----
        if (tid == 0)
            __hip_atomic_store(&flags[g], t + 2, __ATOMIC_RELAXED, __HIP_MEMORY_SCOPE_AGENT);
        if (t + 1 < SEQ) giStep(t + 1);
    }

    // ---- epilogue: block-local FC partial over its 16 cols, atomicAdd out ----
    float (*hsl)[JPB] = reinterpret_cast<float(*)[JPB]>(&red[0][0][0]);  // [64][16]
    if (gateW) {
#pragma unroll
        for (int r = 0; r < 4; r++) {
            const int b = mtG * 16 + lhi * 4 + r;
            hsl[b][l16] = hp[r];
        }
    }
    __syncthreads();
    if (tid < BATCH * NOUT) {
        const int b = tid / NOUT, o = tid - b * NOUT;
        float acc = (g == 0) ? fc_b[o] : 0.0f;
#pragma unroll
        for (int jl = 0; jl < JPB; jl++)
            acc += hsl[b][jl] * fc_W[(g * JPB + jl) * NOUT + o];
        atomicAdd(&out[tid], acc);
    }
}

// ---------------------------------------------------------------------------
extern "C" void kernel_launch(void* const* d_in, const int* in_sizes, int n_in,
                              void* d_out, int out_size, void* d_ws, size_t ws_size,
                              hipStream_t stream) {
    const int*   text = (const int*)  d_in[0];
    const float* emb  = (const float*)d_in[1];
    const float* W_ih = (const float*)d_in[2];
    const float* W_hh = (const float*)d_in[3];
    const float* b_ih = (const float*)d_in[4];
    const float* b_hh = (const float*)d_in[5];
    const float* fc_W = (const float*)d_in[6];
    const float* fc_b = (const float*)d_in[7];
    float* out = (float*)d_out;

    // ws layout (bytes):
    //   flags [64] int (rounded to 4096)           : 4096
    //   hring [4][4][32][64][8] bf16               : 524288
    //   whh_f [64][3][32][64][8] bf16              : 6291456
    //   wih_f [64][3][16][64][8] bf16              : 3145728
    //   xfrag [512][4][16][64][8] bf16             : 33554432   (~43.6 MB)
    char* ws = (char*)d_ws;
    int*            flags = (int*)(ws);
    unsigned short* hring = (unsigned short*)(ws + 4096);
    unsigned short* whh_f = (unsigned short*)(ws + 4096 + 524288);
    unsigned short* wih_f = (unsigned short*)(ws + 4096 + 524288 + 6291456);
    unsigned short* xfrag = (unsigned short*)(ws + 4096 + 524288 + 6291456 + 3145728);

    hipMemsetAsync(flags, 0, 4096, stream);
    hipMemsetAsync(out, 0, (size_t)out_size * sizeof(float), stream);

    const long nfrag_hh = (long)NBLK * 3 * 32 * 64;   // 393216
    const long nfrag_ih = (long)NBLK * 3 * 16 * 64;   // 196608
    pack_w<<<(int)((nfrag_hh + 255) / 256), 256, 0, stream>>>(W_hh, whh_f, HID);
    pack_w<<<(int)((nfrag_ih + 255) / 256), 256, 0, stream>>>(W_ih, wih_f, EMBD);

    const long nx = (long)SEQ * 4 * 16 * 64;
    embed_x<<<(int)((nx + 255) / 256), 256, 0, stream>>>(text, emb, xfrag);

    void* args[] = { (void*)&xfrag, (void*)&b_ih, (void*)&b_hh,
                     (void*)&fc_W, (void*)&fc_b, (void*)&whh_f, (void*)&wih_f,
                     (void*)&hring, (void*)&flags, (void*)&out };
    hipLaunchCooperativeKernel((void*)gru_mfma, dim3(NBLK), dim3(NTHR), args, 0, stream);
}

// Round 12
// 2994.080 us; speedup vs baseline: 1.3838x; 1.3589x over previous
//
#include <hip/hip_runtime.h>
#include <hip/hip_cooperative_groups.h>
#include <hip/hip_bf16.h>
#include <math.h>

constexpr int EMBD  = 512;
constexpr int HID   = 1024;
constexpr int NOUT  = 5;
constexpr int SEQ   = 512;
constexpr int BATCH = 64;

constexpr int NBLK = 64;    // blocks; block owns 16 hidden cols
constexpr int NTHR = 512;   // 8 waves: (mp in 0..1) x (kq in 0..3)
constexpr int JPB  = 16;    // hidden cols per block

typedef __attribute__((ext_vector_type(8))) short bf16x8;
typedef __attribute__((ext_vector_type(4))) float f32x4;

__device__ inline unsigned short f2bf(float f) {
    __hip_bfloat16 h = __float2bfloat16(f);
    return *reinterpret_cast<unsigned short*>(&h);
}

__device__ inline bf16x8 cvt8v(f32x4 a, f32x4 b) {
    bf16x8 r;
#pragma unroll
    for (int i = 0; i < 4; i++) { __hip_bfloat16 h = __float2bfloat16(a[i]); r[i]     = *reinterpret_cast<short*>(&h); }
#pragma unroll
    for (int i = 0; i < 4; i++) { __hip_bfloat16 h = __float2bfloat16(b[i]); r[4 + i] = *reinterpret_cast<short*>(&h); }
    return r;
}

// Agent-scope (MALL-coherent) 8B ops: h exchange and x reads.
__device__ inline unsigned long long load_a8(const unsigned short* p) {
    return __hip_atomic_load((const unsigned long long*)p,
                             __ATOMIC_RELAXED, __HIP_MEMORY_SCOPE_AGENT);
}
__device__ inline void store_a8(unsigned short* p, unsigned long long v) {
    __hip_atomic_store((unsigned long long*)p, v,
                       __ATOMIC_RELAXED, __HIP_MEMORY_SCOPE_AGENT);
}
__device__ inline bf16x8 load_frag(const unsigned short* p) {
    union { unsigned long long u[2]; bf16x8 v; } r;
    r.u[0] = load_a8(p);
    r.u[1] = load_a8(p + 4);
    return r.v;
}

__device__ inline float sigm(float x) { return 1.f / (1.f + __expf(-x)); }
__device__ inline float ftanh(float x) { return 1.f - 2.f / (1.f + __expf(2.f * x)); }

// ---------------------------------------------------------------------------
// Pack W [K, 3072] fp32 -> bf16 MFMA B-fragments, layout [g][nt][kt][lane][8]
// ---------------------------------------------------------------------------
__global__ __launch_bounds__(256) void pack_w(const float* __restrict__ W,
                                              unsigned short* __restrict__ out,
                                              int K) {
    const int nkt = K / 32;
    long idx = (long)blockIdx.x * 256 + threadIdx.x;
    const long total = (long)NBLK * 3 * nkt * 64;
    if (idx >= total) return;
    const int lane = idx & 63;
    long rest = idx >> 6;
    const int kt = rest % nkt; rest /= nkt;
    const int nt = rest % 3;
    const int g  = rest / 3;
    const int k0  = kt * 32 + (lane >> 4) * 8;
    const int col = nt * HID + g * JPB + (lane & 15);
    unsigned short* o = out + idx * 8;
#pragma unroll
    for (int i = 0; i < 8; i++)
        o[i] = f2bf(W[(long)(k0 + i) * 3072 + col]);
}

// ---------------------------------------------------------------------------
// One-shot embedding into A-FRAGMENT layout:
// xfrag[t][bt(4)][kt(16)][lane(64)][8]
// ---------------------------------------------------------------------------
__global__ __launch_bounds__(256) void embed_x(const int* __restrict__ text,
                                               const float* __restrict__ emb,
                                               unsigned short* __restrict__ xfrag) {
    long idx = (long)blockIdx.x * 256 + threadIdx.x;
    if (idx >= (long)SEQ * 4 * 16 * 64) return;
    const int lane = idx & 63;
    const int kt   = (idx >> 6) & 15;
    const int bt   = (idx >> 10) & 3;
    const int t    = (int)(idx >> 12);
    const int b    = bt * 16 + (lane & 15);
    const int e0   = kt * 32 + (lane >> 4) * 8;
    const int tok  = text[t * BATCH + b];
    const float* s = emb + (long)tok * EMBD + e0;
    *(bf16x8*)(xfrag + idx * 8) = cvt8v(*(const f32x4*)s, *(const f32x4*)(s + 4));
}

// ---------------------------------------------------------------------------
// Persistent GRU (R9 structure) + REGISTER-RESIDENT WEIGHTS:
// each wave preloads its 36 loop-invariant B-fragments (12 gi + 24 gh =
// 144 VGPRs) once; the per-step MFMA loops are pure MFMA + ha-wait.
// Per-step (4 syncs): MFMA -> publish -> sync -> gate waves reduce+gate+hx
// -> sync -> storer waves emit h' frags + drain -> sync -> flag arrive;
// loadX(t+1) via MALL in poll shadow; wave0 polls -> sync.
// ---------------------------------------------------------------------------
__global__ void __launch_bounds__(NTHR, 2) gru_mfma(
    const unsigned short* __restrict__ xfrag,  // [SEQ][4][16][64][8] bf16
    const float*          __restrict__ b_ih,   // [3072]
    const float*          __restrict__ b_hh,   // [3072]
    const float*          __restrict__ fc_W,   // [HID][NOUT]
    const float*          __restrict__ fc_b,   // [NOUT]
    const unsigned short* __restrict__ whh_f,  // [64][3][32][64][8]
    const unsigned short* __restrict__ wih_f,  // [64][3][16][64][8]
    unsigned short*       __restrict__ hbuf,   // [2][4][32][64][8] bf16
    int*                  __restrict__ flags,  // [64] (zeroed)
    float*                __restrict__ out)    // [BATCH][NOUT] (zeroed)
{
    const int g    = blockIdx.x;
    const int tid  = threadIdx.x;
    const int lane = tid & 63;
    const int w    = tid >> 6;
    const int mp   = w >> 2;   // 0..1
    const int kq   = w & 3;    // 0..3
    const int l16  = lane & 15;
    const int lhi  = lane >> 4;

    __shared__ float red[8][8][256];            // 64 KB partial buffer
    __shared__ unsigned short hx[64][20];       // padded h' transpose buffer

    constexpr int HFRAG = 4 * 32 * 64 * 8;      // ushorts per h buffer (64K)

    // zero BOTH h buffers: 512 ull per block
    for (int i = tid; i < 512; i += NTHR)
        store_a8(hbuf + ((long)g * 512 + i) * 4, 0ull);

    // ---- preload loop-invariant B-fragments into registers (144 VGPRs) ----
    const unsigned short* whh_g = whh_f + (long)g * 3 * 32 * 64 * 8;
    const unsigned short* wih_g = wih_f + (long)g * 3 * 16 * 64 * 8;
    bf16x8 wiR[4], wiZ[4], wiN[4];   // gi B-frags (this wave's K-quarter)
    bf16x8 whR[8], whZ[8], whN[8];   // gh B-frags
#pragma unroll
    for (int kk = 0; kk < 4; kk++) {
        const unsigned short* bp = wih_g + (((long)(kq * 4 + kk)) * 64 + lane) * 8;
        wiR[kk] = *(const bf16x8*)(bp);
        wiZ[kk] = *(const bf16x8*)(bp + 16 * 64 * 8);
        wiN[kk] = *(const bf16x8*)(bp + 2 * 16 * 64 * 8);
    }
#pragma unroll
    for (int kk = 0; kk < 8; kk++) {
        const unsigned short* bp = whh_g + (((long)(kq * 8 + kk)) * 64 + lane) * 8;
        whR[kk] = *(const bf16x8*)(bp);
        whZ[kk] = *(const bf16x8*)(bp + 32 * 64 * 8);
        whN[kk] = *(const bf16x8*)(bp + 2 * 32 * 64 * 8);
    }

    // biases for this lane's j (used by gate waves)
    const int jg = g * JPB + l16;
    const float bir  = b_ih[jg],           bhr = b_hh[jg];
    const float biz  = b_ih[HID + jg],     bhz = b_hh[HID + jg];
    const float bin_ = b_ih[2 * HID + jg], bhn = b_hh[2 * HID + jg];

    const bool gateW  = (kq < 2);
    const bool storeW = (kq >= 2);
    const int  mtG    = mp * 2 + kq;         // gate wave's btile (kq<2)
    const int  mtS    = mp * 2 + (kq - 2);   // storer wave's btile (kq>=2)
    float hp[4] = {0.f, 0.f, 0.f, 0.f};      // fp32 carry (gate waves)

    bf16x8 xa0[4], xa1[4];
    auto loadX = [&](int t) {
        const unsigned short* base = xfrag + (long)t * (4 * 16 * 64 * 8);
#pragma unroll
        for (int kk = 0; kk < 4; kk++) {
            const int kt = kq * 4 + kk;
            xa0[kk] = load_frag(base + (((2 * mp + 0) * 16 + kt) * 64 + lane) * 8);
            xa1[kk] = load_frag(base + (((2 * mp + 1) * 16 + kt) * 64 + lane) * 8);
        }
    };

    // storer-wave addressing: lane s covers consumer-lane cl = s>>1, half s&1
    const int sb  = mtS * 16 + ((lane >> 1) & 15);              // source b row
    const int sjl = ((lane >> 1) >> 4) * 8 + 4 * (lane & 1);    // source j-local
    const long sdst = (((long)mtS * 32 + (g >> 1)) * 64) * 8 + 256 * (g & 1) + lane * 4;

    // ---- init barrier ----
    asm volatile("s_waitcnt vmcnt(0)" ::: "memory");
    __syncthreads();
    if (tid == 0)
        __hip_atomic_store(&flags[g], 1, __ATOMIC_RELAXED, __HIP_MEMORY_SCOPE_AGENT);
    loadX(0);
    if (tid < 64) {
        int f = __hip_atomic_load(&flags[tid], __ATOMIC_RELAXED, __HIP_MEMORY_SCOPE_AGENT);
        while (__any(f < 1)) {
            __builtin_amdgcn_s_sleep(1);
            f = __hip_atomic_load(&flags[tid], __ATOMIC_RELAXED, __HIP_MEMORY_SCOPE_AGENT);
        }
    }
    __syncthreads();

    for (int t = 0; t < SEQ; ++t) {
        const unsigned short* hr = hbuf + (long)(t & 1) * HFRAG;
        unsigned short*       hw = hbuf + (long)((t + 1) & 1) * HFRAG;

        // ---- h fragment loads (coalesced; hidden under gi MFMAs) ----
        bf16x8 ha0[8], ha1[8];
#pragma unroll
        for (int kk = 0; kk < 8; kk++) {
            const int kt = kq * 8 + kk;
            ha0[kk] = load_frag(hr + (((long)(2 * mp + 0) * 32 + kt) * 64 + lane) * 8);
            ha1[kk] = load_frag(hr + (((long)(2 * mp + 1) * 32 + kt) * 64 + lane) * 8);
        }

        f32x4 aR0 = {0,0,0,0}, aR1 = {0,0,0,0};
        f32x4 aZ0 = {0,0,0,0}, aZ1 = {0,0,0,0};
        f32x4 aGh0 = {0,0,0,0}, aGh1 = {0,0,0,0};
        f32x4 aGi0 = {0,0,0,0}, aGi1 = {0,0,0,0};

        // ---- gi: x_t @ W_ih (weights in registers) ----
#pragma unroll
        for (int kk = 0; kk < 4; kk++) {
            aR0  = __builtin_amdgcn_mfma_f32_16x16x32_bf16(xa0[kk], wiR[kk], aR0, 0, 0, 0);
            aR1  = __builtin_amdgcn_mfma_f32_16x16x32_bf16(xa1[kk], wiR[kk], aR1, 0, 0, 0);
            aZ0  = __builtin_amdgcn_mfma_f32_16x16x32_bf16(xa0[kk], wiZ[kk], aZ0, 0, 0, 0);
            aZ1  = __builtin_amdgcn_mfma_f32_16x16x32_bf16(xa1[kk], wiZ[kk], aZ1, 0, 0, 0);
            aGi0 = __builtin_amdgcn_mfma_f32_16x16x32_bf16(xa0[kk], wiN[kk], aGi0, 0, 0, 0);
            aGi1 = __builtin_amdgcn_mfma_f32_16x16x32_bf16(xa1[kk], wiN[kk], aGi1, 0, 0, 0);
        }

        // ---- gh: h_t @ W_hh (weights in registers) ----
#pragma unroll
        for (int kk = 0; kk < 8; kk++) {
            aR0  = __builtin_amdgcn_mfma_f32_16x16x32_bf16(ha0[kk], whR[kk], aR0, 0, 0, 0);
            aR1  = __builtin_amdgcn_mfma_f32_16x16x32_bf16(ha1[kk], whR[kk], aR1, 0, 0, 0);
            aZ0  = __builtin_amdgcn_mfma_f32_16x16x32_bf16(ha0[kk], whZ[kk], aZ0, 0, 0, 0);
            aZ1  = __builtin_amdgcn_mfma_f32_16x16x32_bf16(ha1[kk], whZ[kk], aZ1, 0, 0, 0);
            aGh0 = __builtin_amdgcn_mfma_f32_16x16x32_bf16(ha0[kk], whN[kk], aGh0, 0, 0, 0);
            aGh1 = __builtin_amdgcn_mfma_f32_16x16x32_bf16(ha1[kk], whN[kk], aGh1, 0, 0, 0);
        }

        // ---- publish partials ----
        *(f32x4*)&red[w][0][lane * 4] = aR0;
        *(f32x4*)&red[w][1][lane * 4] = aR1;
        *(f32x4*)&red[w][2][lane * 4] = aZ0;
        *(f32x4*)&red[w][3][lane * 4] = aZ1;
        *(f32x4*)&red[w][4][lane * 4] = aGh0;
        *(f32x4*)&red[w][5][lane * 4] = aGh1;
        *(f32x4*)&red[w][6][lane * 4] = aGi0;
        *(f32x4*)&red[w][7][lane * 4] = aGi1;
        __syncthreads();

        // ---- gate waves: reduce one btile, gates, carry, write hx ----
        if (gateW) {
            const int s = kq;
            f32x4 R  = {0,0,0,0}, Z = {0,0,0,0}, Gh = {0,0,0,0}, Gi = {0,0,0,0};
#pragma unroll
            for (int q = 0; q < 4; q++) {
                const int src = mp * 4 + q;
                R  += *(const f32x4*)&red[src][0 + s][lane * 4];
                Z  += *(const f32x4*)&red[src][2 + s][lane * 4];
                Gh += *(const f32x4*)&red[src][4 + s][lane * 4];
                Gi += *(const f32x4*)&red[src][6 + s][lane * 4];
            }
#pragma unroll
            for (int r = 0; r < 4; r++) {
                const float rr = sigm(R[r] + bir + bhr);
                const float zz = sigm(Z[r] + biz + bhz);
                const float nn = ftanh(Gi[r] + bin_ + rr * (Gh[r] + bhn));
                const float hn = (1.f - zz) * nn + zz * hp[r];
                hp[r] = hn;
                hx[mtG * 16 + lhi * 4 + r][l16] = f2bf(hn);
            }
        }
        __syncthreads();

        // ---- storer waves: emit h' fragments (512B contiguous per btile) ----
        if (storeW) {
            const unsigned long long v =
                *(const unsigned long long*)&hx[sb][sjl];
            store_a8(hw + sdst, v);
            asm volatile("s_waitcnt vmcnt(0)" ::: "memory");
        }
        __syncthreads();

        // ---- flag arrive; x prefetch (MALL) in shadow; poll; release ----
        if (tid == 0)
            __hip_atomic_store(&flags[g], t + 2, __ATOMIC_RELAXED, __HIP_MEMORY_SCOPE_AGENT);
        loadX((t + 1 < SEQ) ? t + 1 : SEQ - 1);
        if (tid < 64) {
            int f = __hip_atomic_load(&flags[tid], __ATOMIC_RELAXED, __HIP_MEMORY_SCOPE_AGENT);
            while (__any(f < t + 2)) {
                __builtin_amdgcn_s_sleep(1);
                f = __hip_atomic_load(&flags[tid], __ATOMIC_RELAXED, __HIP_MEMORY_SCOPE_AGENT);
            }
        }
        __syncthreads();
    }

    // ---- epilogue: block-local FC partial over its 16 cols, atomicAdd out ----
    float (*hsl)[JPB] = reinterpret_cast<float(*)[JPB]>(&red[0][0][0]);  // [64][16]
    if (gateW) {
#pragma unroll
        for (int r = 0; r < 4; r++) {
            const int b = mtG * 16 + lhi * 4 + r;
            hsl[b][l16] = hp[r];
        }
    }
    __syncthreads();
    if (tid < BATCH * NOUT) {
        const int b = tid / NOUT, o = tid - b * NOUT;
        float acc = (g == 0) ? fc_b[o] : 0.0f;
#pragma unroll
        for (int jl = 0; jl < JPB; jl++)
            acc += hsl[b][jl] * fc_W[(g * JPB + jl) * NOUT + o];
        atomicAdd(&out[tid], acc);
    }
}

// ---------------------------------------------------------------------------
extern "C" void kernel_launch(void* const* d_in, const int* in_sizes, int n_in,
                              void* d_out, int out_size, void* d_ws, size_t ws_size,
                              hipStream_t stream) {
    const int*   text = (const int*)  d_in[0];
    const float* emb  = (const float*)d_in[1];
    const float* W_ih = (const float*)d_in[2];
    const float* W_hh = (const float*)d_in[3];
    const float* b_ih = (const float*)d_in[4];
    const float* b_hh = (const float*)d_in[5];
    const float* fc_W = (const float*)d_in[6];
    const float* fc_b = (const float*)d_in[7];
    float* out = (float*)d_out;

    // ws layout (bytes):
    //   flags [64] int (rounded to 4096)           : 4096
    //   hbuf  [2][4][32][64][8] bf16               : 262144
    //   whh_f [64][3][32][64][8] bf16              : 6291456
    //   wih_f [64][3][16][64][8] bf16              : 3145728
    //   xfrag [512][4][16][64][8] bf16             : 33554432   (~43.3 MB)
    char* ws = (char*)d_ws;
    int*            flags = (int*)(ws);
    unsigned short* hbuf  = (unsigned short*)(ws + 4096);
    unsigned short* whh_f = (unsigned short*)(ws + 4096 + 262144);
    unsigned short* wih_f = (unsigned short*)(ws + 4096 + 262144 + 6291456);
    unsigned short* xfrag = (unsigned short*)(ws + 4096 + 262144 + 6291456 + 3145728);

    hipMemsetAsync(flags, 0, 4096, stream);
    hipMemsetAsync(out, 0, (size_t)out_size * sizeof(float), stream);

    const long nfrag_hh = (long)NBLK * 3 * 32 * 64;   // 393216
    const long nfrag_ih = (long)NBLK * 3 * 16 * 64;   // 196608
    pack_w<<<(int)((nfrag_hh + 255) / 256), 256, 0, stream>>>(W_hh, whh_f, HID);
    pack_w<<<(int)((nfrag_ih + 255) / 256), 256, 0, stream>>>(W_ih, wih_f, EMBD);

    const long nx = (long)SEQ * 4 * 16 * 64;
    embed_x<<<(int)((nx + 255) / 256), 256, 0, stream>>>(text, emb, xfrag);

    void* args[] = { (void*)&xfrag, (void*)&b_ih, (void*)&b_hh,
                     (void*)&fc_W, (void*)&fc_b, (void*)&whh_f, (void*)&wih_f,
                     (void*)&hbuf, (void*)&flags, (void*)&out };
    hipLaunchCooperativeKernel((void*)gru_mfma, dim3(NBLK), dim3(NTHR), args, 0, stream);
}